// Round 2
// baseline (3312.722 us; speedup 1.0000x reference)
//
#include <hip/hip_runtime.h>
#include <math.h>

// SSIM via fully separable pipeline, u/v-reformulated, software-pipelined.
// img1,img2: [32,3,512,512] fp32 -> scalar mean.
//
// Round-4 change: SSIM needs only 4 convolutions, not 6:
//   u = x+y, v = x-y;  U=E[u], V=E[v], P=E[u^2], Q=E[v^2]
//   mu1*mu2        = (U^2-V^2)/4      mu1^2+mu2^2       = (U^2+V^2)/2
//   E[xy]          = (P-Q)/4          E[x^2]+E[y^2]     = (P+Q)/2
// Stage planes {u, v, u^2, v^2} in LDS (squares computed ONCE per input
// pixel at commit time), so h-conv = 4 fma/tap (was 7 ops/tap over 5
// quantities) and v-conv ring = 4x11 (was 5x11). IEEE divide replaced by
// v_rcp + 1 Newton step. ~25% fewer VALU instructions per output; the
// kernel is VALU-issue-bound (VALUBusy 84%, HBM 10%, 0 bank conflicts).
//
// Kept from round 3 (T14, verified +92us): global loads for rows r+2,r+3
// ISSUED into registers right after the barrier, ~2 rows of conv math run,
// then registers are COMMITTED to LDS. 2 rows per barrier, 4-row LDS ring.
// ring phase r%11 compile-time (pair period 22 == 0 mod 11).
//
// Round-2 lesson: __launch_bounds__(256,4) (128-VGPR cap) forced the ring
// into scratch (WRITE_SIZE 711 MB). Cap at 256 VGPRs instead.

#define IH 512
#define IW 512
#define NCH 96            // 32*3 depthwise channels
#define TW 256            // tile width == blockDim.x
#define TH 34             // output rows per block
#define SSTR 272          // LDS row stride (266 used)
#define TYB 16            // ceil(512/34) block-rows
#define C1f (0.01f * 0.01f)
#define C2f (0.03f * 0.03f)

struct Weights { float w[11]; };

__global__ __launch_bounds__(256, 2) void ssim_kernel(
    const float* __restrict__ img1, const float* __restrict__ img2,
    float* __restrict__ partial, Weights wt)
{
    __shared__ float sU [4][SSTR];   // 4-row ring, buffer = row & 3
    __shared__ float sV [4][SSTR];
    __shared__ float sUU[4][SSTR];
    __shared__ float sVV[4][SSTR];
    __shared__ float wave_sums[4];

    const int tid = threadIdx.x;
    const int bx  = blockIdx.x;
    const int tx  = bx & 1;          // 2 col tiles
    const int ty  = (bx >> 1) & 15;  // 16 row tiles
    const int ch  = bx >> 5;         // 96 channels

    const int col0     = tx * TW;
    const int row_out0 = ty * TH;
    const int row0     = row_out0 - 5;       // staging row r -> global row row0+r
    const size_t choff = (size_t)ch * IH * IW;

    // column halo indices (fixed per thread)
    const int  gc0   = col0 - 5 + tid;
    const bool colv0 = ((unsigned)gc0 < (unsigned)IW);
    const int  gc1   = gc0 + TW;                   // staged by tid < 10
    const bool colv1 = ((unsigned)gc1 < (unsigned)IW);
    const bool halo  = (tid < 10);

    // two register staging slots (fixed names -> no runtime reg indexing)
    float pa0, pb0, pa1, pb1;        // slot P: even row of the pair
    float qa0, qb0, qa1, qb1;        // slot Q: odd row of the pair

    auto issue = [&](int r, float& a0, float& b0, float& a1, float& b1) {
        const int gr = row0 + r;                   // wave-uniform
        const bool rowv = ((unsigned)gr < (unsigned)IH);
        const long rowoff = (long)choff + (long)gr * IW;
        a0 = 0.f; b0 = 0.f; a1 = 0.f; b1 = 0.f;
        if (rowv & colv0) {
            a0 = img1[rowoff + gc0];
            b0 = img2[rowoff + gc0];
        }
        if (rowv & colv1 & halo) {
            a1 = img1[rowoff + gc1];
            b1 = img2[rowoff + gc1];
        }
    };
    // commit: compute u,v,u^2,v^2 ONCE per staged pixel, write 4 planes.
    auto commit = [&](int r, float a0, float b0, float a1, float b1) {
        const int p = r & 3;
        const float u0 = a0 + b0, v0 = a0 - b0;
        sU [p][tid] = u0;
        sV [p][tid] = v0;
        sUU[p][tid] = u0 * u0;
        sVV[p][tid] = v0 * v0;
        if (halo) {
            const float u1 = a1 + b1, v1 = a1 - b1;
            sU [p][tid + TW] = u1;
            sV [p][tid + TW] = v1;
            sUU[p][tid + TW] = u1 * u1;
            sVV[p][tid + TW] = v1 * v1;
        }
    };

    // accumulator ring: slot s holds output row o with o % 11 == s.
    // Zero-init only to avoid reading junk in the (discarded) warm-up emits.
    float accU[11], accV[11], accP[11], accQ[11];
    #pragma unroll
    for (int s = 0; s < 11; ++s)
        accU[s] = accV[s] = accP[s] = accQ[s] = 0.f;

    float tsum = 0.f;

    // prologue: rows 0,1 staged (one-time full-latency wait)
    issue(0, pa0, pb0, pa1, pb1);
    issue(1, qa0, qb0, qa1, qb1);
    commit(0, pa0, pb0, pa1, pb1);
    commit(1, qa0, qb0, qa1, qb1);

    for (int g = 0; g < 2; ++g) {
        #pragma unroll
        for (int jj = 0; jj < 11; ++jj) {
            const int rp = g * 22 + jj * 2;   // this pair computes rows rp, rp+1
            __syncthreads();                  // prev commits visible; prev reads done

            const bool more = (rp + 2) < 44;  // wave-uniform
            if (more) {
                issue(rp + 2, pa0, pb0, pa1, pb1);
                issue(rp + 3, qa0, qb0, qa1, qb1);
            }

            #pragma unroll
            for (int e = 0; e < 2; ++e) {
                const int r  = rp + e;
                const int ph = (2 * jj + e) % 11;   // == r % 11, compile-time
                const int p  = r & 3;               // LDS ring buffer (runtime ok)

                // ---- horizontal 11-tap conv: 4 fma per tap ----
                const float* __restrict__ rowU  = &sU [p][tid];
                const float* __restrict__ rowV  = &sV [p][tid];
                const float* __restrict__ rowUU = &sUU[p][tid];
                const float* __restrict__ rowVV = &sVV[p][tid];
                float hu = 0.f, hv = 0.f, hp = 0.f, hq = 0.f;
                #pragma unroll
                for (int k = 0; k < 11; ++k) {
                    const float wk = wt.w[k];
                    hu = fmaf(wk, rowU [k], hu);
                    hv = fmaf(wk, rowV [k], hv);
                    hp = fmaf(wk, rowUU[k], hp);
                    hq = fmaf(wk, rowVV[k], hq);
                }

                // ---- vertical conv: scatter into ring, weight idx (ph-s) mod 11.
                //      wi==0 is the first tap of the slot's window -> assign. ----
                #pragma unroll
                for (int s = 0; s < 11; ++s) {
                    const int wi = (ph - s + 11) % 11;   // compile-time
                    const float wk = wt.w[wi];
                    if (wi == 0) {
                        accU[s] = wk * hu;
                        accV[s] = wk * hv;
                        accP[s] = wk * hp;
                        accQ[s] = wk * hq;
                    } else {
                        accU[s] = fmaf(wk, hu, accU[s]);
                        accV[s] = fmaf(wk, hv, accV[s]);
                        accP[s] = fmaf(wk, hp, accP[s]);
                        accQ[s] = fmaf(wk, hq, accQ[s]);
                    }
                }

                // ---- emit output row o = r-10 (slot (ph+1)%11) ----
                const int se = (ph + 1) % 11;           // compile-time
                const float Uo = accU[se], Vo = accV[se];
                const float Po = accP[se], Qo = accQ[se];

                const float A   = Uo * Uo;              // U^2
                const float B   = Vo * Vo;              // V^2
                const float ApB = A + B;
                const float AmB = A - B;
                const float PpQ = Po + Qo;
                const float PmQ = Po - Qo;
                // num = (2*mu12 + C1) * (2*sigma12 + C2)
                const float numl = fmaf(0.5f, AmB, C1f);
                const float numr = fmaf(0.5f, PmQ - AmB, C2f);
                // den = (mu1^2+mu2^2 + C1) * (sigma1^2+sigma2^2 + C2)
                const float denl = fmaf(0.5f, ApB, C1f);
                const float denr = fmaf(0.5f, PpQ - ApB, C2f);
                const float num = numl * numr;
                const float den = denl * denr;

                // fast reciprocal: v_rcp (~1 ulp) + 1 Newton step
                float rrcp = __builtin_amdgcn_rcpf(den);
                rrcp = rrcp * fmaf(-den, rrcp, 2.0f);

                const int o = r - 10;
                const bool valid = (o >= 0) && (row_out0 + o < IH);
                tsum += valid ? (num * rrcp) : 0.f;
            }

            // ---- commit the prefetched pair: vmcnt wait covered by the
            //      conv math above. Loads never cross the barrier. ----
            if (more) {
                commit(rp + 2, pa0, pb0, pa1, pb1);
                commit(rp + 3, qa0, qb0, qa1, qb1);
            }
        }
    }

    // ---- block reduction ----
    #pragma unroll
    for (int off = 32; off > 0; off >>= 1)
        tsum += __shfl_down(tsum, off);
    if ((tid & 63) == 0) wave_sums[tid >> 6] = tsum;
    __syncthreads();
    if (tid == 0) {
        partial[blockIdx.x] =
            wave_sums[0] + wave_sums[1] + wave_sums[2] + wave_sums[3];
    }
}

__global__ __launch_bounds__(256) void reduce_kernel(
    const float* __restrict__ partial, int n, float* __restrict__ out,
    double inv_count)
{
    __shared__ double wave_sums[4];
    const int tid = threadIdx.x;
    double s = 0.0;
    for (int i = tid; i < n; i += 256) s += (double)partial[i];
    #pragma unroll
    for (int off = 32; off > 0; off >>= 1)
        s += __shfl_down(s, off);
    if ((tid & 63) == 0) wave_sums[tid >> 6] = s;
    __syncthreads();
    if (tid == 0) {
        out[0] = (float)((wave_sums[0] + wave_sums[1] +
                          wave_sums[2] + wave_sums[3]) * inv_count);
    }
}

extern "C" void kernel_launch(void* const* d_in, const int* in_sizes, int n_in,
                              void* d_out, int out_size, void* d_ws, size_t ws_size,
                              hipStream_t stream)
{
    const float* img1 = (const float*)d_in[0];
    const float* img2 = (const float*)d_in[1];
    float* out = (float*)d_out;
    float* partial = (float*)d_ws;   // 3072 floats = 12 KB scratch

    // Gaussian window (ws=11, sigma=1.5) in fp32, matching the reference
    Weights wt;
    {
        float s = 0.f;
        for (int i = 0; i < 11; ++i) {
            const float d = (float)(i - 5);
            wt.w[i] = expf(-(d * d) / 4.5f);
            s += wt.w[i];
        }
        for (int i = 0; i < 11; ++i) wt.w[i] /= s;
    }

    const int nblocks = NCH * TYB * 2;   // 3072

    ssim_kernel<<<nblocks, 256, 0, stream>>>(img1, img2, partial, wt);

    const double inv_count = 1.0 / ((double)NCH * IH * IW);
    reduce_kernel<<<1, 256, 0, stream>>>(partial, nblocks, out, inv_count);
}